// Round 1
// baseline (950.596 us; speedup 1.0000x reference)
//
#include <hip/hip_runtime.h>
#include <cstddef>

// Problem constants (from reference): B=32, N_SEL=20000, N_VOX=40000, IN=128, PLANES=32
static constexpr int kNB     = 32;
static constexpr int kNSel   = 20000;
static constexpr int kIn     = 128;
static constexpr int kPlanes = 32;

typedef __attribute__((ext_vector_type(8))) short short8;   // 8 bf16 = 4 VGPRs (MFMA A/B frag)
typedef __attribute__((ext_vector_type(4))) float f32x4;    // MFMA C/D frag

// round-to-nearest-even fp32 -> bf16 (no NaN handling needed: inputs are normal randoms)
__device__ __forceinline__ short f2bf(float f) {
    unsigned int u = __builtin_bit_cast(unsigned int, f);
    u += 0x7fffu + ((u >> 16) & 1u);
    return (short)(u >> 16);
}

// One wave handles one selected voxel n:
//   h[32b x 32o] = x[:, n, :] (32x128) @ w0[vidx] (128x32) / 128 + b0[vidx]; GELU(exact)
//   out[:, n]    = h @ w1[vidx] / 32 + b1[vidx]
// MFMA tiling: 2x2 tiles of 16x16x32 bf16, K=128 in 4 steps. No LDS.
__global__ __launch_bounds__(256) void voxel_mlp_kernel(
    const float* __restrict__ x,     // [32][20000][128]
    const int*   __restrict__ vind,  // [20000]
    const float* __restrict__ w0,    // [40000][128][32]
    const float* __restrict__ b0,    // [40000][32]
    const float* __restrict__ w1,    // [40000][32]
    const float* __restrict__ b1,    // [40000]
    float*       __restrict__ out)   // [32][20000]
{
    const int lane = threadIdx.x & 63;
    const int n    = blockIdx.x * 4 + (threadIdx.x >> 6);  // 4 waves = 4 voxels per block
    const int c    = lane & 15;   // col / m-index within 16
    const int q    = lane >> 4;   // quad 0..3

    const int vidx = vind[n];
    const float* wv = w0 + (size_t)vidx * (kIn * kPlanes);

    f32x4 acc[2][2];
    #pragma unroll
    for (int rt = 0; rt < 2; ++rt)
        #pragma unroll
        for (int ct = 0; ct < 2; ++ct)
            acc[rt][ct] = f32x4{0.f, 0.f, 0.f, 0.f};

    #pragma unroll
    for (int ks = 0; ks < 4; ++ks) {
        const int k0 = ks * 32 + q * 8;   // this lane's 8-wide K slice within the 32-wide step

        // A fragments: A[m=lane&15][k=q*8+j]  ->  x[b = rt*16+c][n][k0 .. k0+7], contiguous
        short8 afrag[2];
        #pragma unroll
        for (int rt = 0; rt < 2; ++rt) {
            const float* p = x + ((size_t)(rt * 16 + c) * kNSel + n) * kIn + k0;
            const f32x4 f0 = *(const f32x4*)p;
            const f32x4 f1 = *(const f32x4*)(p + 4);
            short8 a;
            a[0] = f2bf(f0[0]); a[1] = f2bf(f0[1]); a[2] = f2bf(f0[2]); a[3] = f2bf(f0[3]);
            a[4] = f2bf(f1[0]); a[5] = f2bf(f1[1]); a[6] = f2bf(f1[2]); a[7] = f2bf(f1[3]);
            afrag[rt] = a;
        }

        // B fragments: B[k=q*8+j][nn=lane&15] -> w0[vidx][k0+j][ct*16+c], stride 32 floats
        short8 bfrag[2];
        #pragma unroll
        for (int ct = 0; ct < 2; ++ct) {
            const float* p = wv + (size_t)k0 * kPlanes + ct * 16 + c;
            short8 bq;
            #pragma unroll
            for (int j = 0; j < 8; ++j) bq[j] = f2bf(p[j * kPlanes]);
            bfrag[ct] = bq;
        }

        #pragma unroll
        for (int rt = 0; rt < 2; ++rt)
            #pragma unroll
            for (int ct = 0; ct < 2; ++ct)
                acc[rt][ct] = __builtin_amdgcn_mfma_f32_16x16x32_bf16(
                    afrag[rt], bfrag[ct], acc[rt][ct], 0, 0, 0);
    }

    // ---- Epilogue ----
    // C/D layout: col = lane&15 (o within tile), row = q*4 + reg (b within tile)
    const float b0v[2] = { b0[(size_t)vidx * kPlanes + c],
                           b0[(size_t)vidx * kPlanes + 16 + c] };
    const float w1v[2] = { w1[(size_t)vidx * kPlanes + c],
                           w1[(size_t)vidx * kPlanes + 16 + c] };
    const float b1v = b1[vidx];

    float pr[2][4];
    #pragma unroll
    for (int rt = 0; rt < 2; ++rt) {
        #pragma unroll
        for (int r = 0; r < 4; ++r) {
            float s = 0.f;
            #pragma unroll
            for (int ct = 0; ct < 2; ++ct) {
                const float h = acc[rt][ct][r] * (1.0f / 128.0f) + b0v[ct];
                const float g = 0.5f * h * (1.0f + erff(h * 0.70710678118654752440f));
                s += g * w1v[ct];
            }
            pr[rt][r] = s;  // partial over this lane's 2 o-values; b = rt*16 + q*4 + r
        }
    }

    // Reduce over o: sum across the 16 lanes sharing the same quad (xor of low 4 lane bits)
    #pragma unroll
    for (int m = 1; m < 16; m <<= 1) {
        #pragma unroll
        for (int rt = 0; rt < 2; ++rt)
            #pragma unroll
            for (int r = 0; r < 4; ++r)
                pr[rt][r] += __shfl_xor(pr[rt][r], m, 64);
    }

    // 8 lanes (c<8) each write one b-row result for this quad's 4-row group
    if (c < 8) {
        const int rt = c >> 2;
        const int r  = c & 3;
        const int b  = rt * 16 + q * 4 + r;
        out[(size_t)b * kNSel + n] = pr[rt][r] * (1.0f / 32.0f) + b1v;
    }
}

extern "C" void kernel_launch(void* const* d_in, const int* in_sizes, int n_in,
                              void* d_out, int out_size, void* d_ws, size_t ws_size,
                              hipStream_t stream) {
    const float* x    = (const float*)d_in[0];
    const int*   vind = (const int*)  d_in[1];
    const float* w0   = (const float*)d_in[2];
    const float* b0   = (const float*)d_in[3];
    const float* w1   = (const float*)d_in[4];
    const float* b1   = (const float*)d_in[5];
    float* out = (float*)d_out;

    dim3 grid(kNSel / 4);   // 20000 voxels, 4 per block (one per wave)
    dim3 block(256);
    voxel_mlp_kernel<<<grid, block, 0, stream>>>(x, vind, w0, b0, w1, b1, out);
}